// Round 4
// baseline (261.066 us; speedup 1.0000x reference)
//
#include <hip/hip_runtime.h>
#include <hip/hip_bf16.h>
#include <stdint.h>

#define N_TOTAL 8192
#define HALF_N  4096
#define DIM     512
#define INV_TAU (1.0f/0.07f)

typedef __attribute__((ext_vector_type(8))) short short8;
typedef __attribute__((ext_vector_type(4))) float f32x4;

#define AS1 __attribute__((address_space(1)))
#define AS3 __attribute__((address_space(3)))

// ---------------- Kernel 0: row-normalize, emit bf16 z ----------------
__global__ __launch_bounds__(256) void norm_kernel(const float* __restrict__ z1,
                                                   const float* __restrict__ z2,
                                                   ushort* __restrict__ zb)
{
    int row  = blockIdx.x * 4 + (threadIdx.x >> 6);
    int lane = threadIdx.x & 63;
    const float* src = (row < HALF_N) ? (z1 + (size_t)row * DIM)
                                      : (z2 + (size_t)(row - HALF_N) * DIM);
    const float4* p = (const float4*)src;
    float4 a = p[lane * 2];
    float4 b = p[lane * 2 + 1];
    float ss = a.x*a.x + a.y*a.y + a.z*a.z + a.w*a.w
             + b.x*b.x + b.y*b.y + b.z*b.z + b.w*b.w;
#pragma unroll
    for (int o = 1; o < 64; o <<= 1) ss += __shfl_xor(ss, o);
    float sc = 1.0f / fmaxf(sqrtf(ss), 1e-12f);

    float v[8] = {a.x*sc, a.y*sc, a.z*sc, a.w*sc, b.x*sc, b.y*sc, b.z*sc, b.w*sc};
    alignas(16) ushort u[8];
#pragma unroll
    for (int j = 0; j < 8; j++) {
        __hip_bfloat16 h = __float2bfloat16(v[j]);
        u[j] = *(ushort*)&h;
    }
    *(uint4*)(zb + (size_t)row * DIM + lane * 8) = *(const uint4*)u;
}

// ---------------- Kernel 1: 128x128 bf16 MFMA GEMM (sim = z z^T) ------
// 2-phase double-buffered staging (one barrier per K-step), LDS XOR-swizzle
// realized via pre-swizzled GLOBAL source (global_load_lds writes linearly):
//   LDS 16B-unit (row, s) holds logical chunk q = s ^ ((row>>1)&3).
// Epilogue: rowsum += sum_j exp(sim/tau) (diag excluded); cross-half sims
// stored as monotone u16 keys: key = h ^ (sign ? 0xFFFF : 0x8000).
__global__ __launch_bounds__(256) void gemm_kernel(const ushort* __restrict__ zb,
                                                   float* __restrict__ rowsum,
                                                   ushort* __restrict__ keys)
{
    __shared__ ushort As[2][128 * 32];
    __shared__ ushort Bs[2][128 * 32];

    const int t    = threadIdx.x;
    const int w    = t >> 6;
    const int lane = t & 63;
    const int wr   = w >> 1, wc = w & 1;       // 2x2 waves of 64x64
    const int brow = blockIdx.y * 128;
    const int bcol = blockIdx.x * 128;

    f32x4 acc[4][4] = {};

    // staging: 16B unit c = row*4 + s; fetch logical q = s ^ ((row>>1)&3)
    const int c0 = t, c1 = 256 + t;
    const int r0 = c0 >> 2, r1 = c1 >> 2;
    const int q0 = (c0 & 3) ^ ((r0 >> 1) & 3);
    const int q1 = (c1 & 3) ^ ((r1 >> 1) & 3);
    const size_t gaA0 = (size_t)(brow + r0) * DIM + q0 * 8;
    const size_t gaA1 = (size_t)(brow + r1) * DIM + q1 * 8;
    const size_t gaB0 = (size_t)(bcol + r0) * DIM + q0 * 8;
    const size_t gaB1 = (size_t)(bcol + r1) * DIM + q1 * 8;
    const int l0 = (w * 64) * 16;        // wave-uniform LDS byte base
    const int l1 = (256 + w * 64) * 16;

#define STAGE(buf, ko) do {                                                        \
    __builtin_amdgcn_global_load_lds((const AS1 uint32_t*)(zb + gaA0 + (ko)),      \
        (AS3 uint32_t*)((char*)As[buf] + l0), 16, 0, 0);                           \
    __builtin_amdgcn_global_load_lds((const AS1 uint32_t*)(zb + gaA1 + (ko)),      \
        (AS3 uint32_t*)((char*)As[buf] + l1), 16, 0, 0);                           \
    __builtin_amdgcn_global_load_lds((const AS1 uint32_t*)(zb + gaB0 + (ko)),      \
        (AS3 uint32_t*)((char*)Bs[buf] + l0), 16, 0, 0);                           \
    __builtin_amdgcn_global_load_lds((const AS1 uint32_t*)(zb + gaB1 + (ko)),      \
        (AS3 uint32_t*)((char*)Bs[buf] + l1), 16, 0, 0);                           \
} while (0)

    STAGE(0, 0);
    __syncthreads();

    int cur = 0;
    for (int kt = 0; kt < DIM / 32; ++kt) {
        if (kt + 1 < DIM / 32) STAGE(cur ^ 1, (kt + 1) * 32);

        short8 av[4], bv[4];
#pragma unroll
        for (int m = 0; m < 4; m++) {
            int ro = wr * 64 + m * 16 + (lane & 15);
            int s  = (lane >> 4) ^ ((ro >> 1) & 3);
            av[m] = *(const short8*)((const char*)As[cur] + (ro * 4 + s) * 16);
        }
#pragma unroll
        for (int n = 0; n < 4; n++) {
            int ro = wc * 64 + n * 16 + (lane & 15);
            int s  = (lane >> 4) ^ ((ro >> 1) & 3);
            bv[n] = *(const short8*)((const char*)Bs[cur] + (ro * 4 + s) * 16);
        }
#pragma unroll
        for (int m = 0; m < 4; m++)
#pragma unroll
            for (int n = 0; n < 4; n++)
                acc[m][n] = __builtin_amdgcn_mfma_f32_16x16x32_bf16(av[m], bv[n], acc[m][n], 0, 0, 0);

        __syncthreads();   // drains vmcnt(0): next buffer staged, this one free
        cur ^= 1;
    }
#undef STAGE

    // ---- epilogue ----
    const bool is_cross = (brow < HALF_N) != (bcol < HALF_N);
    const int  croff    = (brow < HALF_N) ? HALF_N : 0;

#pragma unroll
    for (int m = 0; m < 4; m++) {
#pragma unroll
        for (int r = 0; r < 4; r++) {
            int grow = brow + wr * 64 + m * 16 + ((lane >> 4) << 2) + r;
            float rs = 0.f;
#pragma unroll
            for (int n = 0; n < 4; n++) {
                int gcol = bcol + wc * 64 + n * 16 + (lane & 15);
                float v  = acc[m][n][r];
                float e  = (grow == gcol) ? 0.f : __expf(v * INV_TAU);
                rs += e;
                if (is_cross) {
                    ushort h;
                    *(_Float16*)&h = (_Float16)v;
                    ushort key = h ^ (ushort)((ushort)((short)h >> 15) | 0x8000);
                    keys[(size_t)grow * HALF_N + (gcol - croff)] = key;
                }
            }
            rs += __shfl_xor(rs, 1);
            rs += __shfl_xor(rs, 2);
            rs += __shfl_xor(rs, 4);
            rs += __shfl_xor(rs, 8);
            if ((lane & 15) == 0) atomicAdd(&rowsum[grow], rs);
        }
    }
}

// ---------------- Kernel 2: per-row top-10 + loss ----------------------
// Per-lane top-2 scan (3 ops/elem), then top-10 extraction from the
// 128-candidate union. Exact unless a lane holds >=3 of the row's true
// top-10 (~3% of rows; replacement error ~1e-5 in the final loss).
__device__ __forceinline__ uint32_t umax32(uint32_t a, uint32_t b) { return a > b ? a : b; }
__device__ __forceinline__ uint32_t umin32(uint32_t a, uint32_t b) { return a < b ? a : b; }

__device__ __forceinline__ float decode_key(uint32_t key)
{
    ushort h = (key & 0x8000u) ? (ushort)(key ^ 0x8000u) : (ushort)(key ^ 0xFFFFu);
    return (float)(*(_Float16*)&h);
}

__global__ __launch_bounds__(256) void topk_loss_kernel(const ushort* __restrict__ keys,
                                                        const float* __restrict__ rowsum,
                                                        float* __restrict__ out)
{
    int i    = blockIdx.x * 4 + (threadIdx.x >> 6);
    int lane = threadIdx.x & 63;
    const ushort* row = keys + (size_t)i * HALF_N;

    // issue all 8 loads up front (ILP), then scan from registers
    uint4 uu[8];
#pragma unroll
    for (int p = 0; p < 8; p++)
        uu[p] = *(const uint4*)(row + p * 512 + lane * 8);

    uint32_t t1 = 0u, t2 = 0u;   // per-lane top-2, packed (key<<16)|(4095-idx)
#pragma unroll
    for (int p = 0; p < 8; p++) {
        uint32_t wd[4] = {uu[p].x, uu[p].y, uu[p].z, uu[p].w};
        uint32_t invb = (uint32_t)(4095 - (p * 512 + lane * 8));
#pragma unroll
        for (int j = 0; j < 4; j++) {
            uint32_t x0 = ((wd[j] & 0xFFFFu) << 16) | (invb - 2u * j);
            uint32_t x1 = ((wd[j] >> 16) << 16)     | (invb - 2u * j - 1u);
            uint32_t mn0 = umin32(t1, x0); t1 = umax32(t1, x0); t2 = umax32(t2, mn0);
            uint32_t mn1 = umin32(t1, x1); t1 = umax32(t1, x1); t2 = umax32(t2, mn1);
        }
    }

    // extract global top-10 from the 128-candidate union
    int posidx = i & (HALF_N - 1);
    float S10 = 0.f; int posflag = 0;
#pragma unroll
    for (int tc = 0; tc < 10; tc++) {
        uint32_t b = umax32(t1, t2);
#pragma unroll
        for (int o = 32; o; o >>= 1)
            b = umax32(b, __shfl_xor(b, o));
        bool w1 = (b == t1);
        bool w2 = (b == t2);
        t1 = w1 ? t2 : t1;
        t2 = (w1 | w2) ? 0u : t2;

        int idx = 4095 - (int)(b & 0xFFFFu);
        S10 += decode_key(b >> 16);
        posflag |= (idx == posidx) ? 1 : 0;
    }

    if (lane == 0) {
        float pos_sim = decode_key((uint32_t)row[posidx]);
        float lse = logf(rowsum[i]);
        float L   = 1.0f + 0.75f * (10 - posflag);
        float sll = INV_TAU * (pos_sim + 0.75f * (S10 - posflag * pos_sim));
        float contrib = L * lse - sll;
        atomicAdd(out, contrib * (1.0f / N_TOTAL));
    }
}

extern "C" void kernel_launch(void* const* d_in, const int* in_sizes, int n_in,
                              void* d_out, int out_size, void* d_ws, size_t ws_size,
                              hipStream_t stream)
{
    const float* z1 = (const float*)d_in[0];
    const float* z2 = (const float*)d_in[1];
    float* out = (float*)d_out;

    char* ws = (char*)d_ws;
    ushort* zb     = (ushort*)ws;                           //  8 MB  (8192x512 bf16)
    float*  rowsum = (float*)(ws + 8388608);                // 32 KB
    ushort* keys   = (ushort*)(ws + 8421376);               // 64 MB  (8192x4096 u16 keys)

    hipMemsetAsync(rowsum, 0, N_TOTAL * sizeof(float), stream);
    hipMemsetAsync(out, 0, out_size * sizeof(float), stream);

    norm_kernel<<<N_TOTAL / 4, 256, 0, stream>>>(z1, z2, zb);
    gemm_kernel<<<dim3(N_TOTAL / 128, N_TOTAL / 128), 256, 0, stream>>>(zb, rowsum, keys);
    topk_loss_kernel<<<N_TOTAL / 4, 256, 0, stream>>>(keys, rowsum, out);
}

// Round 5
// 172.043 us; speedup vs baseline: 1.5174x; 1.5174x over previous
//
#include <hip/hip_runtime.h>
#include <hip/hip_bf16.h>
#include <stdint.h>

#define N_TOTAL 8192
#define HALF_N  4096
#define DIM     512
#define INV_TAU (1.0f/0.07f)

typedef __attribute__((ext_vector_type(8))) short short8;
typedef __attribute__((ext_vector_type(4))) float f32x4;

#define AS1 __attribute__((address_space(1)))
#define AS3 __attribute__((address_space(3)))

__device__ __forceinline__ uint32_t umax32(uint32_t a, uint32_t b) { return a > b ? a : b; }
__device__ __forceinline__ uint32_t umin32(uint32_t a, uint32_t b) { return a < b ? a : b; }

__device__ __forceinline__ float decode_key(uint32_t key)
{
    ushort h = (key & 0x8000u) ? (ushort)(key ^ 0x8000u) : (ushort)(key ^ 0xFFFFu);
    return (float)(*(_Float16*)&h);
}

// ---------------- Kernel 0: row-normalize, emit bf16 z ----------------
__global__ __launch_bounds__(256) void norm_kernel(const float* __restrict__ z1,
                                                   const float* __restrict__ z2,
                                                   ushort* __restrict__ zb)
{
    int row  = blockIdx.x * 4 + (threadIdx.x >> 6);
    int lane = threadIdx.x & 63;
    const float* src = (row < HALF_N) ? (z1 + (size_t)row * DIM)
                                      : (z2 + (size_t)(row - HALF_N) * DIM);
    const float4* p = (const float4*)src;
    float4 a = p[lane * 2];
    float4 b = p[lane * 2 + 1];
    float ss = a.x*a.x + a.y*a.y + a.z*a.z + a.w*a.w
             + b.x*b.x + b.y*b.y + b.z*b.z + b.w*b.w;
#pragma unroll
    for (int o = 1; o < 64; o <<= 1) ss += __shfl_xor(ss, o);
    float sc = 1.0f / fmaxf(sqrtf(ss), 1e-12f);

    float v[8] = {a.x*sc, a.y*sc, a.z*sc, a.w*sc, b.x*sc, b.y*sc, b.z*sc, b.w*sc};
    alignas(16) ushort u[8];
#pragma unroll
    for (int j = 0; j < 8; j++) {
        __hip_bfloat16 h = __float2bfloat16(v[j]);
        u[j] = *(ushort*)&h;
    }
    *(uint4*)(zb + (size_t)row * DIM + lane * 8) = *(const uint4*)u;
}

// ---------------- Kernel 1: 128x128 bf16 MFMA GEMM (sim = z z^T) ------
// 2-phase double-buffered staging, pre-swizzled-source LDS layout.
// Fused epilogue (NO sim materialization):
//   - rowsum += sum_j exp(sim/tau)  (diag excluded)
//   - per-(wave,row) top-2 over 64 cross cols -> partial[8192][64] uint2
//   - pos_sim[row] = exact f32 sim of the positive pair
__global__ __launch_bounds__(256) void gemm_kernel(const ushort* __restrict__ zb,
                                                   float* __restrict__ rowsum,
                                                   uint2* __restrict__ partial,
                                                   float* __restrict__ pos_sim)
{
    __shared__ ushort As[2][128 * 32];
    __shared__ ushort Bs[2][128 * 32];

    const int t    = threadIdx.x;
    const int w    = t >> 6;
    const int lane = t & 63;
    const int wr   = w >> 1, wc = w & 1;       // 2x2 waves of 64x64
    const int brow = blockIdx.y * 128;
    const int bcol = blockIdx.x * 128;

    f32x4 acc[4][4] = {};

    // staging: 16B unit c = row*4 + s; fetch logical q = s ^ ((row>>1)&3)
    const int c0 = t, c1 = 256 + t;
    const int r0 = c0 >> 2, r1 = c1 >> 2;
    const int q0 = (c0 & 3) ^ ((r0 >> 1) & 3);
    const int q1 = (c1 & 3) ^ ((r1 >> 1) & 3);
    const size_t gaA0 = (size_t)(brow + r0) * DIM + q0 * 8;
    const size_t gaA1 = (size_t)(brow + r1) * DIM + q1 * 8;
    const size_t gaB0 = (size_t)(bcol + r0) * DIM + q0 * 8;
    const size_t gaB1 = (size_t)(bcol + r1) * DIM + q1 * 8;
    const int l0 = (w * 64) * 16;
    const int l1 = (256 + w * 64) * 16;

#define STAGE(buf, ko) do {                                                        \
    __builtin_amdgcn_global_load_lds((const AS1 uint32_t*)(zb + gaA0 + (ko)),      \
        (AS3 uint32_t*)((char*)As[buf] + l0), 16, 0, 0);                           \
    __builtin_amdgcn_global_load_lds((const AS1 uint32_t*)(zb + gaA1 + (ko)),      \
        (AS3 uint32_t*)((char*)As[buf] + l1), 16, 0, 0);                           \
    __builtin_amdgcn_global_load_lds((const AS1 uint32_t*)(zb + gaB0 + (ko)),      \
        (AS3 uint32_t*)((char*)Bs[buf] + l0), 16, 0, 0);                           \
    __builtin_amdgcn_global_load_lds((const AS1 uint32_t*)(zb + gaB1 + (ko)),      \
        (AS3 uint32_t*)((char*)Bs[buf] + l1), 16, 0, 0);                           \
} while (0)

    STAGE(0, 0);
    __syncthreads();

    int cur = 0;
    for (int kt = 0; kt < DIM / 32; ++kt) {
        if (kt + 1 < DIM / 32) STAGE(cur ^ 1, (kt + 1) * 32);

        short8 av[4], bv[4];
#pragma unroll
        for (int m = 0; m < 4; m++) {
            int ro = wr * 64 + m * 16 + (lane & 15);
            int s  = (lane >> 4) ^ ((ro >> 1) & 3);
            av[m] = *(const short8*)((const char*)As[cur] + (ro * 4 + s) * 16);
        }
#pragma unroll
        for (int n = 0; n < 4; n++) {
            int ro = wc * 64 + n * 16 + (lane & 15);
            int s  = (lane >> 4) ^ ((ro >> 1) & 3);
            bv[n] = *(const short8*)((const char*)Bs[cur] + (ro * 4 + s) * 16);
        }
#pragma unroll
        for (int m = 0; m < 4; m++)
#pragma unroll
            for (int n = 0; n < 4; n++)
                acc[m][n] = __builtin_amdgcn_mfma_f32_16x16x32_bf16(av[m], bv[n], acc[m][n], 0, 0, 0);

        __syncthreads();
        cur ^= 1;
    }
#undef STAGE

    // ---- epilogue ----
    const bool is_cross = (brow < HALF_N) != (bcol < HALF_N);
    const int  croff    = (brow < HALF_N) ? HALF_N : 0;
    const int  cb       = is_cross ? ((bcol - croff) >> 7) : 0;

#pragma unroll
    for (int m = 0; m < 4; m++) {
#pragma unroll
        for (int r = 0; r < 4; r++) {
            int grow = brow + wr * 64 + m * 16 + ((lane >> 4) << 2) + r;
            float rs = 0.f;
            uint32_t t1 = 0u, t2 = 0u;
#pragma unroll
            for (int n = 0; n < 4; n++) {
                int gcol = bcol + wc * 64 + n * 16 + (lane & 15);
                float v  = acc[m][n][r];
                float e  = (grow == gcol) ? 0.f : __expf(v * INV_TAU);
                rs += e;
                if (is_cross) {
                    int cidx = gcol - croff;
                    ushort h;
                    *(_Float16*)&h = (_Float16)v;
                    ushort key = h ^ (ushort)((ushort)((short)h >> 15) | 0x8000);
                    uint32_t x = ((uint32_t)key << 16) | (uint32_t)(4095 - cidx);
                    uint32_t mn = umin32(t1, x);
                    t1 = umax32(t1, x);
                    t2 = umax32(t2, mn);
                    if (cidx == (grow & (HALF_N - 1))) pos_sim[grow] = v;
                }
            }
            rs += __shfl_xor(rs, 1);
            rs += __shfl_xor(rs, 2);
            rs += __shfl_xor(rs, 4);
            rs += __shfl_xor(rs, 8);
            if ((lane & 15) == 0) atomicAdd(&rowsum[grow], rs);

            if (is_cross) {
                // merge top-2 across the 16-lane group (sorted-pair merge)
#pragma unroll
                for (int o = 1; o < 16; o <<= 1) {
                    uint32_t o1 = __shfl_xor(t1, o);
                    uint32_t o2 = __shfl_xor(t2, o);
                    uint32_t nt2 = umax32(umin32(t1, o1), umax32(t2, o2));
                    t1 = umax32(t1, o1);
                    t2 = nt2;
                }
                if ((lane & 15) == 0)
                    partial[((size_t)grow << 6) + cb * 2 + wc] = make_uint2(t1, t2);
            }
        }
    }
}

// ---------------- Kernel 2: per-row top-10 + per-row loss --------------
// Reads 64 uint2 partials per row (128 candidates), extracts top-10 via
// 10 rounds of wave-max. Writes contrib[row] — NO global atomics.
__global__ __launch_bounds__(256) void topk_loss_kernel(const uint2* __restrict__ partial,
                                                        const float* __restrict__ pos_sim,
                                                        const float* __restrict__ rowsum,
                                                        float* __restrict__ contrib)
{
    int i    = blockIdx.x * 4 + (threadIdx.x >> 6);
    int lane = threadIdx.x & 63;

    uint2 p = partial[((size_t)i << 6) + lane];
    uint32_t t1 = p.x, t2 = p.y;

    int posidx = i & (HALF_N - 1);
    float S10 = 0.f; int posflag = 0;
#pragma unroll
    for (int tc = 0; tc < 10; tc++) {
        uint32_t b = umax32(t1, t2);
#pragma unroll
        for (int o = 32; o; o >>= 1)
            b = umax32(b, __shfl_xor(b, o));
        bool w1 = (b == t1);
        bool w2 = (b == t2);
        t1 = w1 ? t2 : t1;
        t2 = (w1 | w2) ? 0u : t2;

        int idx = 4095 - (int)(b & 0xFFFFu);
        S10 += decode_key(b >> 16);
        posflag |= (idx == posidx) ? 1 : 0;
    }

    if (lane == 0) {
        float ps  = pos_sim[i];
        float lse = logf(rowsum[i]);
        float L   = 1.0f + 0.75f * (10 - posflag);
        float sll = INV_TAU * (ps + 0.75f * (S10 - posflag * ps));
        contrib[i] = L * lse - sll;
    }
}

// ---------------- Kernel 3: deterministic final reduce -----------------
__global__ __launch_bounds__(256) void reduce_kernel(const float* __restrict__ contrib,
                                                     float* __restrict__ out)
{
    int t = threadIdx.x;
    float s = 0.f;
    for (int j = t; j < N_TOTAL; j += 256) s += contrib[j];
#pragma unroll
    for (int o = 1; o < 64; o <<= 1) s += __shfl_xor(s, o);
    __shared__ float wsum[4];
    if ((t & 63) == 0) wsum[t >> 6] = s;
    __syncthreads();
    if (t == 0) out[0] = (wsum[0] + wsum[1] + wsum[2] + wsum[3]) * (1.0f / N_TOTAL);
}

extern "C" void kernel_launch(void* const* d_in, const int* in_sizes, int n_in,
                              void* d_out, int out_size, void* d_ws, size_t ws_size,
                              hipStream_t stream)
{
    const float* z1 = (const float*)d_in[0];
    const float* z2 = (const float*)d_in[1];
    float* out = (float*)d_out;

    char* ws = (char*)d_ws;
    ushort* zb      = (ushort*)ws;                     //  8 MB   8192x512 bf16
    float*  rowsum  = (float*)(ws + 8388608);          // 32 KB
    float*  pos_sim = (float*)(ws + 8421376);          // 32 KB
    uint2*  partial = (uint2*)(ws + 8454144);          //  4 MB   8192x64 uint2
    float*  contrib = (float*)(ws + 12648448);         // 32 KB

    hipMemsetAsync(rowsum, 0, N_TOTAL * sizeof(float), stream);

    norm_kernel<<<N_TOTAL / 4, 256, 0, stream>>>(z1, z2, zb);
    gemm_kernel<<<dim3(N_TOTAL / 128, N_TOTAL / 128), 256, 0, stream>>>(zb, rowsum, partial, pos_sim);
    topk_loss_kernel<<<N_TOTAL / 4, 256, 0, stream>>>(partial, pos_sim, rowsum, contrib);
    reduce_kernel<<<1, 256, 0, stream>>>(contrib, out);
}

// Round 6
// 133.530 us; speedup vs baseline: 1.9551x; 1.2884x over previous
//
#include <hip/hip_runtime.h>
#include <hip/hip_bf16.h>
#include <stdint.h>

#define N_TOTAL 8192
#define HALF_N  4096
#define DIM     512
#define INV_TAU (1.0f/0.07f)

typedef __attribute__((ext_vector_type(8))) short short8;
typedef __attribute__((ext_vector_type(4))) float f32x4;

#define AS1 __attribute__((address_space(1)))
#define AS3 __attribute__((address_space(3)))

__device__ __forceinline__ uint32_t umax32(uint32_t a, uint32_t b) { return a > b ? a : b; }
__device__ __forceinline__ uint32_t umin32(uint32_t a, uint32_t b) { return a < b ? a : b; }

__device__ __forceinline__ float decode_key(uint32_t key)
{
    ushort h = (key & 0x8000u) ? (ushort)(key ^ 0x8000u) : (ushort)(key ^ 0xFFFFu);
    return (float)(*(_Float16*)&h);
}

__device__ __forceinline__ uint32_t enc_key(float v, int idx)
{
    ushort h;
    *(_Float16*)&h = (_Float16)v;
    ushort key = h ^ (ushort)((ushort)((short)h >> 15) | 0x8000);
    return ((uint32_t)key << 16) | (uint32_t)(4095 - idx);
}

// ---------------- Kernel 0: row-normalize, emit bf16 z ----------------
__global__ __launch_bounds__(256) void norm_kernel(const float* __restrict__ z1,
                                                   const float* __restrict__ z2,
                                                   ushort* __restrict__ zb)
{
    int row  = blockIdx.x * 4 + (threadIdx.x >> 6);
    int lane = threadIdx.x & 63;
    const float* src = (row < HALF_N) ? (z1 + (size_t)row * DIM)
                                      : (z2 + (size_t)(row - HALF_N) * DIM);
    const float4* p = (const float4*)src;
    float4 a = p[lane * 2];
    float4 b = p[lane * 2 + 1];
    float ss = a.x*a.x + a.y*a.y + a.z*a.z + a.w*a.w
             + b.x*b.x + b.y*b.y + b.z*b.z + b.w*b.w;
#pragma unroll
    for (int o = 1; o < 64; o <<= 1) ss += __shfl_xor(ss, o);
    float sc = 1.0f / fmaxf(sqrtf(ss), 1e-12f);

    float v[8] = {a.x*sc, a.y*sc, a.z*sc, a.w*sc, b.x*sc, b.y*sc, b.z*sc, b.w*sc};
    alignas(16) ushort u[8];
#pragma unroll
    for (int j = 0; j < 8; j++) {
        __hip_bfloat16 h = __float2bfloat16(v[j]);
        u[j] = *(ushort*)&h;
    }
    *(uint4*)(zb + (size_t)row * DIM + lane * 8) = *(const uint4*)u;
}

// ---------------- Kernel 1: upper-triangle 128x128 bf16 MFMA GEMM -----
// sim is symmetric: only blocks bx >= by are computed (2080 of 4096).
// Row-side epilogue (all blocks): rowsum[grow], top-2 partials, pos_sim.
// Col-side epilogue (bx != by): the transposed tile's rows = our columns:
// rowsum[gcol], col-side top-2 partials, pos_sim — reductions run over
// in-register (m,r) + shfl_xor(16,32), orthogonal to the row side.
__global__ __launch_bounds__(256) void gemm_kernel(const ushort* __restrict__ zb,
                                                   float* __restrict__ rowsum,
                                                   uint2* __restrict__ partial,
                                                   float* __restrict__ pos_sim)
{
    // triangular decode: bid -> (by, bx), bx >= by, row-major upper triangle
    int bid = blockIdx.x;
    int by = (int)(64.5f - sqrtf(4160.25f - 2.0f * (float)bid));
    int off = 64 * by - (by * (by - 1)) / 2;
    if (off > bid) { --by; off = 64 * by - (by * (by - 1)) / 2; }
    else {
        int offn = 64 * (by + 1) - ((by + 1) * by) / 2;
        if (offn <= bid) { ++by; off = offn; }
    }
    int bx = by + (bid - off);

    const int brow = by * 128;
    const int bcol = bx * 128;

    __shared__ ushort As[2][128 * 32];
    __shared__ ushort Bs[2][128 * 32];

    const int t    = threadIdx.x;
    const int w    = t >> 6;
    const int lane = t & 63;
    const int wr   = w >> 1, wc = w & 1;       // 2x2 waves of 64x64

    f32x4 acc[4][4] = {};

    // staging: 16B unit c = row*4 + s; fetch logical q = s ^ ((row>>1)&3)
    const int c0 = t, c1 = 256 + t;
    const int r0 = c0 >> 2, r1 = c1 >> 2;
    const int q0 = (c0 & 3) ^ ((r0 >> 1) & 3);
    const int q1 = (c1 & 3) ^ ((r1 >> 1) & 3);
    const size_t gaA0 = (size_t)(brow + r0) * DIM + q0 * 8;
    const size_t gaA1 = (size_t)(brow + r1) * DIM + q1 * 8;
    const size_t gaB0 = (size_t)(bcol + r0) * DIM + q0 * 8;
    const size_t gaB1 = (size_t)(bcol + r1) * DIM + q1 * 8;
    const int l0 = (w * 64) * 16;
    const int l1 = (256 + w * 64) * 16;

#define STAGE(buf, ko) do {                                                        \
    __builtin_amdgcn_global_load_lds((const AS1 uint32_t*)(zb + gaA0 + (ko)),      \
        (AS3 uint32_t*)((char*)As[buf] + l0), 16, 0, 0);                           \
    __builtin_amdgcn_global_load_lds((const AS1 uint32_t*)(zb + gaA1 + (ko)),      \
        (AS3 uint32_t*)((char*)As[buf] + l1), 16, 0, 0);                           \
    __builtin_amdgcn_global_load_lds((const AS1 uint32_t*)(zb + gaB0 + (ko)),      \
        (AS3 uint32_t*)((char*)Bs[buf] + l0), 16, 0, 0);                           \
    __builtin_amdgcn_global_load_lds((const AS1 uint32_t*)(zb + gaB1 + (ko)),      \
        (AS3 uint32_t*)((char*)Bs[buf] + l1), 16, 0, 0);                           \
} while (0)

    STAGE(0, 0);
    __syncthreads();

    int cur = 0;
    for (int kt = 0; kt < DIM / 32; ++kt) {
        if (kt + 1 < DIM / 32) STAGE(cur ^ 1, (kt + 1) * 32);

        short8 av[4], bv[4];
#pragma unroll
        for (int m = 0; m < 4; m++) {
            int ro = wr * 64 + m * 16 + (lane & 15);
            int s  = (lane >> 4) ^ ((ro >> 1) & 3);
            av[m] = *(const short8*)((const char*)As[cur] + (ro * 4 + s) * 16);
        }
#pragma unroll
        for (int n = 0; n < 4; n++) {
            int ro = wc * 64 + n * 16 + (lane & 15);
            int s  = (lane >> 4) ^ ((ro >> 1) & 3);
            bv[n] = *(const short8*)((const char*)Bs[cur] + (ro * 4 + s) * 16);
        }
#pragma unroll
        for (int m = 0; m < 4; m++)
#pragma unroll
            for (int n = 0; n < 4; n++)
                acc[m][n] = __builtin_amdgcn_mfma_f32_16x16x32_bf16(av[m], bv[n], acc[m][n], 0, 0, 0);

        __syncthreads();
        cur ^= 1;
    }
#undef STAGE

    // is_cross: by < 32 <= bx  (first-half rows, second-half cols)
    const bool is_cross = (brow < HALF_N) && (bcol >= HALF_N);

    // ---- pass 1: row side (all blocks) ----
#pragma unroll
    for (int m = 0; m < 4; m++) {
#pragma unroll
        for (int r = 0; r < 4; r++) {
            int grow = brow + wr * 64 + m * 16 + ((lane >> 4) << 2) + r;
            float rs = 0.f;
            uint32_t t1 = 0u, t2 = 0u;
#pragma unroll
            for (int n = 0; n < 4; n++) {
                int gcol = bcol + wc * 64 + n * 16 + (lane & 15);
                float v  = acc[m][n][r];
                float e  = (grow == gcol) ? 0.f : __expf(v * INV_TAU);
                rs += e;
                if (is_cross) {
                    int cidx = gcol - HALF_N;
                    uint32_t x = enc_key(v, cidx);
                    uint32_t mn = umin32(t1, x);
                    t1 = umax32(t1, x);
                    t2 = umax32(t2, mn);
                    if (cidx == grow) pos_sim[grow] = v;
                }
            }
            rs += __shfl_xor(rs, 1);
            rs += __shfl_xor(rs, 2);
            rs += __shfl_xor(rs, 4);
            rs += __shfl_xor(rs, 8);
            if ((lane & 15) == 0) atomicAdd(&rowsum[grow], rs);

            if (is_cross) {
#pragma unroll
                for (int o = 1; o < 16; o <<= 1) {
                    uint32_t o1 = __shfl_xor(t1, o);
                    uint32_t o2 = __shfl_xor(t2, o);
                    uint32_t nt2 = umax32(umin32(t1, o1), umax32(t2, o2));
                    t1 = umax32(t1, o1);
                    t2 = nt2;
                }
                if ((lane & 15) == 0)
                    partial[((size_t)grow << 6) + (bx - 32) * 2 + wc] = make_uint2(t1, t2);
            }
        }
    }

    // ---- pass 2: col side (off-diagonal blocks: transposed tile) ----
    if (bx != by) {
#pragma unroll
        for (int n = 0; n < 4; n++) {
            int gcol = bcol + wc * 64 + n * 16 + (lane & 15);
            float cs = 0.f;
            uint32_t s1 = 0u, s2 = 0u;
#pragma unroll
            for (int m = 0; m < 4; m++) {
#pragma unroll
                for (int r = 0; r < 4; r++) {
                    int grow = brow + wr * 64 + m * 16 + ((lane >> 4) << 2) + r;
                    float v = acc[m][n][r];
                    cs += __expf(v * INV_TAU);   // grow==gcol impossible off-diag
                    if (is_cross) {
                        uint32_t x = enc_key(v, grow);
                        uint32_t mn = umin32(s1, x);
                        s1 = umax32(s1, x);
                        s2 = umax32(s2, mn);
                        if (grow == gcol - HALF_N) pos_sim[gcol] = v;
                    }
                }
            }
            cs += __shfl_xor(cs, 16);
            cs += __shfl_xor(cs, 32);
            if (is_cross) {
#pragma unroll
                for (int o = 16; o < 64; o <<= 1) {
                    uint32_t o1 = __shfl_xor(s1, o);
                    uint32_t o2 = __shfl_xor(s2, o);
                    uint32_t nt2 = umax32(umin32(s1, o1), umax32(s2, o2));
                    s1 = umax32(s1, o1);
                    s2 = nt2;
                }
            }
            if (lane < 16) {
                atomicAdd(&rowsum[gcol], cs);
                if (is_cross)
                    partial[((size_t)gcol << 6) + by * 2 + wr] = make_uint2(s1, s2);
            }
        }
    }
}

// ---------------- Kernel 2: per-row top-10 + per-row loss --------------
__global__ __launch_bounds__(256) void topk_loss_kernel(const uint2* __restrict__ partial,
                                                        const float* __restrict__ pos_sim,
                                                        const float* __restrict__ rowsum,
                                                        float* __restrict__ contrib)
{
    int i    = blockIdx.x * 4 + (threadIdx.x >> 6);
    int lane = threadIdx.x & 63;

    uint2 p = partial[((size_t)i << 6) + lane];
    uint32_t t1 = p.x, t2 = p.y;

    int posidx = i & (HALF_N - 1);
    float S10 = 0.f; int posflag = 0;
#pragma unroll
    for (int tc = 0; tc < 10; tc++) {
        uint32_t b = umax32(t1, t2);
#pragma unroll
        for (int o = 32; o; o >>= 1)
            b = umax32(b, __shfl_xor(b, o));
        bool w1 = (b == t1);
        bool w2 = (b == t2);
        t1 = w1 ? t2 : t1;
        t2 = (w1 | w2) ? 0u : t2;

        int idx = 4095 - (int)(b & 0xFFFFu);
        S10 += decode_key(b >> 16);
        posflag |= (idx == posidx) ? 1 : 0;
    }

    if (lane == 0) {
        float ps  = pos_sim[i];
        float lse = logf(rowsum[i]);
        float L   = 1.0f + 0.75f * (10 - posflag);
        float sll = INV_TAU * (ps + 0.75f * (S10 - posflag * ps));
        contrib[i] = L * lse - sll;
    }
}

// ---------------- Kernel 3: deterministic final reduce -----------------
__global__ __launch_bounds__(256) void reduce_kernel(const float* __restrict__ contrib,
                                                     float* __restrict__ out)
{
    int t = threadIdx.x;
    float s = 0.f;
    for (int j = t; j < N_TOTAL; j += 256) s += contrib[j];
#pragma unroll
    for (int o = 1; o < 64; o <<= 1) s += __shfl_xor(s, o);
    __shared__ float wsum[4];
    if ((t & 63) == 0) wsum[t >> 6] = s;
    __syncthreads();
    if (t == 0) out[0] = (wsum[0] + wsum[1] + wsum[2] + wsum[3]) * (1.0f / N_TOTAL);
}

extern "C" void kernel_launch(void* const* d_in, const int* in_sizes, int n_in,
                              void* d_out, int out_size, void* d_ws, size_t ws_size,
                              hipStream_t stream)
{
    const float* z1 = (const float*)d_in[0];
    const float* z2 = (const float*)d_in[1];
    float* out = (float*)d_out;

    char* ws = (char*)d_ws;
    ushort* zb      = (ushort*)ws;                     //  8 MB   8192x512 bf16
    float*  rowsum  = (float*)(ws + 8388608);          // 32 KB
    float*  pos_sim = (float*)(ws + 8421376);          // 32 KB
    uint2*  partial = (uint2*)(ws + 8454144);          //  4 MB   8192x64 uint2
    float*  contrib = (float*)(ws + 12648448);         // 32 KB

    hipMemsetAsync(rowsum, 0, N_TOTAL * sizeof(float), stream);

    norm_kernel<<<N_TOTAL / 4, 256, 0, stream>>>(z1, z2, zb);
    gemm_kernel<<<2080, 256, 0, stream>>>(zb, rowsum, partial, pos_sim);
    topk_loss_kernel<<<N_TOTAL / 4, 256, 0, stream>>>(partial, pos_sim, rowsum, contrib);
    reduce_kernel<<<1, 256, 0, stream>>>(contrib, out);
}

// Round 7
// 108.023 us; speedup vs baseline: 2.4168x; 1.2361x over previous
//
#include <hip/hip_runtime.h>
#include <hip/hip_bf16.h>
#include <stdint.h>

#define N_TOTAL 8192
#define HALF_N  4096
#define DIM     512
#define INV_TAU (1.0f/0.07f)

typedef __attribute__((ext_vector_type(8))) short short8;
typedef __attribute__((ext_vector_type(4))) float f32x4;

#define AS1 __attribute__((address_space(1)))
#define AS3 __attribute__((address_space(3)))

__device__ __forceinline__ uint32_t umax32(uint32_t a, uint32_t b) { return a > b ? a : b; }
__device__ __forceinline__ uint32_t umin32(uint32_t a, uint32_t b) { return a < b ? a : b; }

__device__ __forceinline__ float decode_key(uint32_t key)
{
    ushort h = (key & 0x8000u) ? (ushort)(key ^ 0x8000u) : (ushort)(key ^ 0xFFFFu);
    return (float)(*(_Float16*)&h);
}

// ---------------- Kernel 0: row-normalize, emit bf16 z ----------------
__global__ __launch_bounds__(256) void norm_kernel(const float* __restrict__ z1,
                                                   const float* __restrict__ z2,
                                                   ushort* __restrict__ zb)
{
    int row  = blockIdx.x * 4 + (threadIdx.x >> 6);
    int lane = threadIdx.x & 63;
    const float* src = (row < HALF_N) ? (z1 + (size_t)row * DIM)
                                      : (z2 + (size_t)(row - HALF_N) * DIM);
    const float4* p = (const float4*)src;
    float4 a = p[lane * 2];
    float4 b = p[lane * 2 + 1];
    float ss = a.x*a.x + a.y*a.y + a.z*a.z + a.w*a.w
             + b.x*b.x + b.y*b.y + b.z*b.z + b.w*b.w;
#pragma unroll
    for (int o = 1; o < 64; o <<= 1) ss += __shfl_xor(ss, o);
    float sc = 1.0f / fmaxf(sqrtf(ss), 1e-12f);

    float v[8] = {a.x*sc, a.y*sc, a.z*sc, a.w*sc, b.x*sc, b.y*sc, b.z*sc, b.w*sc};
    alignas(16) ushort u[8];
#pragma unroll
    for (int j = 0; j < 8; j++) {
        __hip_bfloat16 h = __float2bfloat16(v[j]);
        u[j] = *(ushort*)&h;
    }
    *(uint4*)(zb + (size_t)row * DIM + lane * 8) = *(const uint4*)u;
}

// ---------------- Kernel 1: upper-triangle 128x128 bf16 MFMA GEMM -----
// Only blocks bx >= by computed (2080 of 4096), XCD-swizzled (2080 = 8*260).
// SINGLE-pass epilogue: row-side and col-side reductions share the same
// exp() and fp16 key — col sums cs[n] and col top-2 s1/s2[n] are folded
// into the row-side inner loop (no exp/enc recompute, no second acc scan).
__global__ __launch_bounds__(256, 4) void gemm_kernel(const ushort* __restrict__ zb,
                                                      float* __restrict__ rowsum,
                                                      uint2* __restrict__ partial,
                                                      float* __restrict__ pos_sim)
{
    // XCD-aware swizzle: each XCD gets a contiguous run of 260 triangular ids
    int orig = blockIdx.x;
    int bid  = (orig & 7) * 260 + (orig >> 3);

    // triangular decode: bid -> (by, bx), bx >= by, row-major upper triangle
    int by = (int)(64.5f - sqrtf(4160.25f - 2.0f * (float)bid));
    int off = 64 * by - (by * (by - 1)) / 2;
    if (off > bid) { --by; off = 64 * by - (by * (by - 1)) / 2; }
    else {
        int offn = 64 * (by + 1) - ((by + 1) * by) / 2;
        if (offn <= bid) { ++by; off = offn; }
    }
    int bx = by + (bid - off);

    const int brow = by * 128;
    const int bcol = bx * 128;

    __shared__ ushort As[2][128 * 32];
    __shared__ ushort Bs[2][128 * 32];

    const int t    = threadIdx.x;
    const int w    = t >> 6;
    const int lane = t & 63;
    const int wr   = w >> 1, wc = w & 1;       // 2x2 waves of 64x64

    f32x4 acc[4][4] = {};

    // staging: 16B unit c = row*4 + s; fetch logical q = s ^ ((row>>1)&3)
    const int c0 = t, c1 = 256 + t;
    const int r0 = c0 >> 2, r1 = c1 >> 2;
    const int q0 = (c0 & 3) ^ ((r0 >> 1) & 3);
    const int q1 = (c1 & 3) ^ ((r1 >> 1) & 3);
    const size_t gaA0 = (size_t)(brow + r0) * DIM + q0 * 8;
    const size_t gaA1 = (size_t)(brow + r1) * DIM + q1 * 8;
    const size_t gaB0 = (size_t)(bcol + r0) * DIM + q0 * 8;
    const size_t gaB1 = (size_t)(bcol + r1) * DIM + q1 * 8;
    const int l0 = (w * 64) * 16;
    const int l1 = (256 + w * 64) * 16;

#define STAGE(buf, ko) do {                                                        \
    __builtin_amdgcn_global_load_lds((const AS1 uint32_t*)(zb + gaA0 + (ko)),      \
        (AS3 uint32_t*)((char*)As[buf] + l0), 16, 0, 0);                           \
    __builtin_amdgcn_global_load_lds((const AS1 uint32_t*)(zb + gaA1 + (ko)),      \
        (AS3 uint32_t*)((char*)As[buf] + l1), 16, 0, 0);                           \
    __builtin_amdgcn_global_load_lds((const AS1 uint32_t*)(zb + gaB0 + (ko)),      \
        (AS3 uint32_t*)((char*)Bs[buf] + l0), 16, 0, 0);                           \
    __builtin_amdgcn_global_load_lds((const AS1 uint32_t*)(zb + gaB1 + (ko)),      \
        (AS3 uint32_t*)((char*)Bs[buf] + l1), 16, 0, 0);                           \
} while (0)

    STAGE(0, 0);
    __syncthreads();

    int cur = 0;
    for (int kt = 0; kt < DIM / 32; ++kt) {
        if (kt + 1 < DIM / 32) STAGE(cur ^ 1, (kt + 1) * 32);

        short8 av[4], bv[4];
#pragma unroll
        for (int m = 0; m < 4; m++) {
            int ro = wr * 64 + m * 16 + (lane & 15);
            int s  = (lane >> 4) ^ ((ro >> 1) & 3);
            av[m] = *(const short8*)((const char*)As[cur] + (ro * 4 + s) * 16);
        }
#pragma unroll
        for (int n = 0; n < 4; n++) {
            int ro = wc * 64 + n * 16 + (lane & 15);
            int s  = (lane >> 4) ^ ((ro >> 1) & 3);
            bv[n] = *(const short8*)((const char*)Bs[cur] + (ro * 4 + s) * 16);
        }
#pragma unroll
        for (int m = 0; m < 4; m++)
#pragma unroll
            for (int n = 0; n < 4; n++)
                acc[m][n] = __builtin_amdgcn_mfma_f32_16x16x32_bf16(av[m], bv[n], acc[m][n], 0, 0, 0);

        __syncthreads();
        cur ^= 1;
    }
#undef STAGE

    const bool is_cross = (brow < HALF_N) && (bcol >= HALF_N);
    const bool off_diag = (bx != by);

    float    cs[4] = {0.f, 0.f, 0.f, 0.f};          // col-side exp sums
    uint32_t s1[4] = {0u, 0u, 0u, 0u};              // col-side top-2
    uint32_t s2[4] = {0u, 0u, 0u, 0u};

    // ---- single fused epilogue pass ----
#pragma unroll
    for (int m = 0; m < 4; m++) {
#pragma unroll
        for (int r = 0; r < 4; r++) {
            int grow = brow + wr * 64 + m * 16 + ((lane >> 4) << 2) + r;
            float rs = 0.f;
            uint32_t t1 = 0u, t2 = 0u;
#pragma unroll
            for (int n = 0; n < 4; n++) {
                int gcol = bcol + wc * 64 + n * 16 + (lane & 15);
                float v  = acc[m][n][r];
                float e  = (grow == gcol) ? 0.f : __expf(v * INV_TAU);
                rs += e;
                cs[n] += e;
                if (is_cross) {
                    int cidx = gcol - HALF_N;
                    ushort h;
                    *(_Float16*)&h = (_Float16)v;
                    uint32_t key = ((uint32_t)(ushort)(h ^ (ushort)((ushort)((short)h >> 15) | 0x8000))) << 16;
                    uint32_t xr = key | (uint32_t)(4095 - cidx);   // row-side: col index
                    uint32_t mn = umin32(t1, xr);
                    t1 = umax32(t1, xr);
                    t2 = umax32(t2, mn);
                    uint32_t xc = key | (uint32_t)(4095 - grow);   // col-side: row index
                    mn = umin32(s1[n], xc);
                    s1[n] = umax32(s1[n], xc);
                    s2[n] = umax32(s2[n], mn);
                    if (cidx == grow) { pos_sim[grow] = v; pos_sim[gcol] = v; }
                }
            }
            rs += __shfl_xor(rs, 1);
            rs += __shfl_xor(rs, 2);
            rs += __shfl_xor(rs, 4);
            rs += __shfl_xor(rs, 8);
            if ((lane & 15) == 0) atomicAdd(&rowsum[grow], rs);

            if (is_cross) {
#pragma unroll
                for (int o = 1; o < 16; o <<= 1) {
                    uint32_t o1 = __shfl_xor(t1, o);
                    uint32_t o2 = __shfl_xor(t2, o);
                    uint32_t nt2 = umax32(umin32(t1, o1), umax32(t2, o2));
                    t1 = umax32(t1, o1);
                    t2 = nt2;
                }
                if ((lane & 15) == 0)
                    partial[((size_t)grow << 6) + (bx - 32) * 2 + wc] = make_uint2(t1, t2);
            }
        }
    }

    // ---- col-side finalize (reduce over lane bits 4,5 = row groups) ----
    if (off_diag) {
#pragma unroll
        for (int n = 0; n < 4; n++) {
            float c = cs[n];
            c += __shfl_xor(c, 16);
            c += __shfl_xor(c, 32);
            uint32_t a1 = s1[n], a2 = s2[n];
            if (is_cross) {
#pragma unroll
                for (int o = 16; o < 64; o <<= 1) {
                    uint32_t o1 = __shfl_xor(a1, o);
                    uint32_t o2 = __shfl_xor(a2, o);
                    uint32_t nt2 = umax32(umin32(a1, o1), umax32(a2, o2));
                    a1 = umax32(a1, o1);
                    a2 = nt2;
                }
            }
            if (lane < 16) {
                int gcol = bcol + wc * 64 + n * 16 + lane;
                atomicAdd(&rowsum[gcol], c);
                if (is_cross)
                    partial[((size_t)gcol << 6) + by * 2 + wr] = make_uint2(a1, a2);
            }
        }
    }
}

// ---------------- Kernel 2: per-row top-10 + per-row loss --------------
__global__ __launch_bounds__(256) void topk_loss_kernel(const uint2* __restrict__ partial,
                                                        const float* __restrict__ pos_sim,
                                                        const float* __restrict__ rowsum,
                                                        float* __restrict__ contrib)
{
    int i    = blockIdx.x * 4 + (threadIdx.x >> 6);
    int lane = threadIdx.x & 63;

    uint2 p = partial[((size_t)i << 6) + lane];
    uint32_t t1 = p.x, t2 = p.y;

    int posidx = i & (HALF_N - 1);
    float S10 = 0.f; int posflag = 0;
#pragma unroll
    for (int tc = 0; tc < 10; tc++) {
        uint32_t b = umax32(t1, t2);
#pragma unroll
        for (int o = 32; o; o >>= 1)
            b = umax32(b, __shfl_xor(b, o));
        bool w1 = (b == t1);
        bool w2 = (b == t2);
        t1 = w1 ? t2 : t1;
        t2 = (w1 | w2) ? 0u : t2;

        int idx = 4095 - (int)(b & 0xFFFFu);
        S10 += decode_key(b >> 16);
        posflag |= (idx == posidx) ? 1 : 0;
    }

    if (lane == 0) {
        float ps  = pos_sim[i];
        float lse = logf(rowsum[i]);
        float L   = 1.0f + 0.75f * (10 - posflag);
        float sll = INV_TAU * (ps + 0.75f * (S10 - posflag * ps));
        contrib[i] = L * lse - sll;
    }
}

// ---------------- Kernel 3: deterministic final reduce -----------------
__global__ __launch_bounds__(256) void reduce_kernel(const float* __restrict__ contrib,
                                                     float* __restrict__ out)
{
    int t = threadIdx.x;
    float s = 0.f;
    for (int j = t; j < N_TOTAL; j += 256) s += contrib[j];
#pragma unroll
    for (int o = 1; o < 64; o <<= 1) s += __shfl_xor(s, o);
    __shared__ float wsum[4];
    if ((t & 63) == 0) wsum[t >> 6] = s;
    __syncthreads();
    if (t == 0) out[0] = (wsum[0] + wsum[1] + wsum[2] + wsum[3]) * (1.0f / N_TOTAL);
}

extern "C" void kernel_launch(void* const* d_in, const int* in_sizes, int n_in,
                              void* d_out, int out_size, void* d_ws, size_t ws_size,
                              hipStream_t stream)
{
    const float* z1 = (const float*)d_in[0];
    const float* z2 = (const float*)d_in[1];
    float* out = (float*)d_out;

    char* ws = (char*)d_ws;
    ushort* zb      = (ushort*)ws;                     //  8 MB   8192x512 bf16
    float*  rowsum  = (float*)(ws + 8388608);          // 32 KB
    float*  pos_sim = (float*)(ws + 8421376);          // 32 KB
    uint2*  partial = (uint2*)(ws + 8454144);          //  4 MB   8192x64 uint2
    float*  contrib = (float*)(ws + 12648448);         // 32 KB

    hipMemsetAsync(rowsum, 0, N_TOTAL * sizeof(float), stream);

    norm_kernel<<<N_TOTAL / 4, 256, 0, stream>>>(z1, z2, zb);
    gemm_kernel<<<2080, 256, 0, stream>>>(zb, rowsum, partial, pos_sim);
    topk_loss_kernel<<<N_TOTAL / 4, 256, 0, stream>>>(partial, pos_sim, rowsum, contrib);
    reduce_kernel<<<1, 256, 0, stream>>>(contrib, out);
}